// Round 2
// baseline (475.239 us; speedup 1.0000x reference)
//
#include <hip/hip_runtime.h>

// y = x @ W^T + bias. x:[65536,512] f32, W:[512,512] f32, bias:[512] f32.
// R4: barrier-free streaming design.
//   R2/R3 diagnosis: latency-bound (MfmaUtil 11%, VALUBusy 10%, occ 20-27%,
//   HBM 24% peak) -- block-wide barriers every K-step serialize the
//   stage->MFMA phases and ~160 cyc of MFMA can't cover ~900 cyc of load
//   latency. W is only 1 MB, so stage the block's W-slice in LDS ONCE
//   (MFMA-frag-ordered, conflict-free), then stream X global->reg->MFMA
//   with ZERO barriers in the main loop. 16 independent waves/CU self-pace.
//   BN=64 -> 64 KB LDS (static-safe), 2 blocks/CU. XCD swizzle: all 8
//   col-blocks of a row-group on one XCD so X re-reads are L2 hits.

typedef __bf16 bf16x8 __attribute__((ext_vector_type(8)));
typedef float f32x4 __attribute__((ext_vector_type(4)));

#define BN 64    // output cols per block
#define RB 1024  // rows per block (8 waves x 4 strips x 32 rows)

__global__ __launch_bounds__(512, 4)
void linear_stream(const float* __restrict__ X,
                   const float* __restrict__ W,
                   const float* __restrict__ bias,
                   float* __restrict__ Y) {
  constexpr int K = 512, N = 512;

  // W slice, MFMA-frag-ordered: frag (s = k/32, j = col/16); lane l holds
  // W[bn + j*16 + (l&15)][s*32 + (l>>4)*8 + e], e = 0..7 (one bf16x8, 16 B).
  // bf16 element index = ((s*4 + j)*64 + l)*8. Total 16*4*64*8 = 32768 bf16
  // = 64 KB. ds_read_b128 at lane*16 + imm -> conflict-free, all 64 frag
  // offsets (max 64512 B) fold into the 16-bit ds immediate.
  __shared__ __bf16 Ws[16 * 4 * 64 * 8];

  const int tid  = threadIdx.x;
  const int lane = tid & 63;
  const int wave = tid >> 6;

  // XCD swizzle: blocks = 8 col x 64 rowgroups. id = (rg>>3)*64 + c*8 + (rg&7)
  // -> all 8 col-blocks of one rowgroup share id%8 (same XCD under
  // round-robin) -> X re-reads served by that XCD's L2.
  const int bid = blockIdx.x;                  // 0..511
  const int c   = (bid >> 3) & 7;              // col block 0..7
  const int rg  = (bid >> 6) * 8 + (bid & 7);  // row group 0..63
  const int bn  = c * BN;

  // ---- prologue: stage W[bn..bn+63][0..511] as bf16 frags (once) ----
  {
    const int wrow = tid >> 3;        // 0..63 (row within slice; coalesced)
    const int kc   = (tid & 7) * 64;  // 64-float k-chunk per thread
    const float* wp = W + (size_t)(bn + wrow) * K + kc;
    const int j  = wrow >> 4;
    const int fr = wrow & 15;
#pragma unroll
    for (int g = 0; g < 8; ++g) {
      f32x4 w0 = *(const f32x4*)(wp + g * 8);
      f32x4 w1 = *(const f32x4*)(wp + g * 8 + 4);
      bf16x8 bv;
#pragma unroll
      for (int e = 0; e < 4; ++e) {
        bv[e]     = (__bf16)w0[e];
        bv[e + 4] = (__bf16)w1[e];
      }
      const int k0 = kc + g * 8;
      const int s  = k0 >> 5;
      const int l  = ((k0 >> 3) & 3) * 16 + fr;
      *(bf16x8*)(&Ws[(size_t)((s * 4 + j) * 64 + l) * 8]) = bv;
    }
  }
  __syncthreads();  // the ONLY barrier in the kernel

  // ---- main loop: stream X, no barriers ----
  const int mrow = lane & 15;          // A row / C col within frag
  const int kq   = (lane >> 4) * 8;    // k offset within frag

  float bj[4];
#pragma unroll
  for (int j = 0; j < 4; ++j) bj[j] = bias[bn + j * 16 + mrow];

  const __bf16* wsl = &Ws[lane * 8];

  // wave handles rows [rg*1024 + wave*128, +128): 4 strips of 32 rows
  const size_t row00 = (size_t)rg * RB + wave * 128;
  const float* xp0 = X + (row00 + mrow) * K + kq;

  f32x4 cur[4], nxt[4];
  cur[0] = *(const f32x4*)(xp0);
  cur[1] = *(const f32x4*)(xp0 + 4);
  cur[2] = *(const f32x4*)(xp0 + 16 * K);
  cur[3] = *(const f32x4*)(xp0 + 16 * K + 4);

  for (int p = 0; p < 4; ++p) {
    const float* xp = xp0 + (size_t)p * 32 * K;
    f32x4 acc[2][4] = {};
#pragma unroll
    for (int s = 0; s < 16; ++s) {
      // prefetch next k-step (or next strip's first k-step at s==15);
      // ~900-cyc HBM latency hides under the cvt+ds_read+MFMA below
      const float* pn = (s < 15) ? (xp + (s + 1) * 32) : (xp + 32 * K);
      if (p < 3 || s < 15) {
        nxt[0] = *(const f32x4*)(pn);
        nxt[1] = *(const f32x4*)(pn + 4);
        nxt[2] = *(const f32x4*)(pn + 16 * K);
        nxt[3] = *(const f32x4*)(pn + 16 * K + 4);
      }
      bf16x8 a0, a1;
#pragma unroll
      for (int e = 0; e < 4; ++e) {
        a0[e]     = (__bf16)cur[0][e];
        a0[e + 4] = (__bf16)cur[1][e];
        a1[e]     = (__bf16)cur[2][e];
        a1[e + 4] = (__bf16)cur[3][e];
      }
      const __bf16* wp8 = wsl + (size_t)s * 4 * 64 * 8;
      bf16x8 b0 = *(const bf16x8*)(wp8);
      bf16x8 b1 = *(const bf16x8*)(wp8 + 64 * 8);
      bf16x8 b2 = *(const bf16x8*)(wp8 + 2 * 64 * 8);
      bf16x8 b3 = *(const bf16x8*)(wp8 + 3 * 64 * 8);
      acc[0][0] = __builtin_amdgcn_mfma_f32_16x16x32_bf16(a0, b0, acc[0][0], 0, 0, 0);
      acc[0][1] = __builtin_amdgcn_mfma_f32_16x16x32_bf16(a0, b1, acc[0][1], 0, 0, 0);
      acc[0][2] = __builtin_amdgcn_mfma_f32_16x16x32_bf16(a0, b2, acc[0][2], 0, 0, 0);
      acc[0][3] = __builtin_amdgcn_mfma_f32_16x16x32_bf16(a0, b3, acc[0][3], 0, 0, 0);
      acc[1][0] = __builtin_amdgcn_mfma_f32_16x16x32_bf16(a1, b0, acc[1][0], 0, 0, 0);
      acc[1][1] = __builtin_amdgcn_mfma_f32_16x16x32_bf16(a1, b1, acc[1][1], 0, 0, 0);
      acc[1][2] = __builtin_amdgcn_mfma_f32_16x16x32_bf16(a1, b2, acc[1][2], 0, 0, 0);
      acc[1][3] = __builtin_amdgcn_mfma_f32_16x16x32_bf16(a1, b3, acc[1][3], 0, 0, 0);
#pragma unroll
      for (int q = 0; q < 4; ++q) cur[q] = nxt[q];
    }
    // strip epilogue: C/D layout col = lane&15 (n), row = (lane>>4)*4 + rr (m)
    const size_t row0 = row00 + (size_t)p * 32;
#pragma unroll
    for (int i2 = 0; i2 < 2; ++i2) {
#pragma unroll
      for (int rr = 0; rr < 4; ++rr) {
        const size_t gr = row0 + i2 * 16 + (lane >> 4) * 4 + rr;
        float* yp = Y + gr * N + bn + mrow;
#pragma unroll
        for (int j = 0; j < 4; ++j)
          __builtin_nontemporal_store(acc[i2][j][rr] + bj[j], yp + j * 16);
      }
    }
  }
}

extern "C" void kernel_launch(void* const* d_in, const int* in_sizes, int n_in,
                              void* d_out, int out_size, void* d_ws, size_t ws_size,
                              hipStream_t stream) {
  const float* X = (const float*)d_in[0];
  const float* W = (const float*)d_in[1];
  const float* b = (const float*)d_in[2];
  float* Y = (float*)d_out;
  linear_stream<<<dim3(512), 512, 0, stream>>>(X, W, b, Y);
}

// Round 3
// 330.082 us; speedup vs baseline: 1.4398x; 1.4398x over previous
//
#include <hip/hip_runtime.h>

// y = x @ W^T + bias. x:[65536,512] f32, W:[512,512] f32, bias:[512] f32.
// R5: barrier-free streaming, register-budget-corrected.
//   R4's failure was __launch_bounds__(512,4) capping VGPRs at 64 -> the
//   prefetch pipeline died (dur 332us, MfmaUtil 0.2%). Same architecture,
//   fixed budget: (512,2) cap 256, lean ~110-reg body so 2 blocks/CU fit.
//   Per block: stage W[bn..bn+63][:] as MFMA frags in LDS ONCE (64 KB),
//   one __syncthreads, then 8 waves independently stream 64 rows of X
//   each: global->reg (1-deep prefetch, pinned by sched_barrier(0)) ->
//   cvt bf16 -> MFMA against LDS W frags. No barriers in the main loop.
//   XCD swizzle: the 8 col-blocks sharing a 512-row X group get block ids
//   differing by 8 within a 64-id window -> same XCD, co-resident -> X
//   re-reads are L2 hits.

typedef __bf16 bf16x8 __attribute__((ext_vector_type(8)));
typedef float f32x4 __attribute__((ext_vector_type(4)));

#define BN 64

__global__ __launch_bounds__(512, 2)
void linear_stream2(const float* __restrict__ X,
                    const float* __restrict__ W,
                    const float* __restrict__ bias,
                    float* __restrict__ Y) {
  constexpr int K = 512, N = 512;

  // W slice, MFMA-frag-ordered: frag (s=k/32, j=col/16); lane l holds
  // W[bn + j*16 + (l&15)][s*32 + (l>>4)*8 + e], e=0..7 (16 B).
  // byte addr = lane*16 + (s*4+j)*1024  (max 65520 -> fits ds imm).
  // ds_read_b128 across 64 lanes = 1024 B contiguous -> conflict-free.
  __shared__ __bf16 Ws[16 * 4 * 64 * 8];  // 64 KB

  const int tid  = threadIdx.x;
  const int lane = tid & 63;
  const int wave = tid >> 6;

  // 1024 blocks = 8 col-tiles x 128 row-groups (512 rows each).
  // id = (rghi<<6) | (c<<3) | rglo : col-sharers of a row-group differ by 8
  // (same XCD under round-robin) and sit in one 64-id window (co-resident).
  const int bid = blockIdx.x;                  // 0..1023
  const int c   = (bid >> 3) & 7;              // col tile 0..7
  const int rg  = (bid >> 6) * 8 + (bid & 7);  // row group 0..127
  const int bn  = c * BN;

  const int mrow = lane & 15;
  const int kq   = (lane >> 4) * 8;

  // wave's 64 rows; strip p in {0,1} covers rows +p*32
  const size_t rowbase = (size_t)rg * 512 + wave * 64;
  const float* xw = X + (rowbase + mrow) * K + kq;

  // issue first X chunk before the barrier (overlaps W staging)
  f32x4 c0 = *(const f32x4*)(xw);
  f32x4 c1 = *(const f32x4*)(xw + 4);
  f32x4 c2 = *(const f32x4*)(xw + 16 * K);
  f32x4 c3 = *(const f32x4*)(xw + 16 * K + 4);

  // ---- stage W slice (once) ----
  {
    const int wrow = tid >> 3;        // 0..63, coalesced rows
    const int kc   = (tid & 7) * 64;  // 64-float k chunk
    const float* wp = W + (size_t)(bn + wrow) * K + kc;
    const int j  = wrow >> 4;
    const int fr = wrow & 15;
#pragma unroll
    for (int g = 0; g < 8; ++g) {
      f32x4 w0 = *(const f32x4*)(wp + g * 8);
      f32x4 w1 = *(const f32x4*)(wp + g * 8 + 4);
      bf16x8 bv;
#pragma unroll
      for (int e = 0; e < 4; ++e) {
        bv[e]     = (__bf16)w0[e];
        bv[e + 4] = (__bf16)w1[e];
      }
      const int k0 = kc + g * 8;
      const int s  = k0 >> 5;
      const int l  = ((k0 >> 3) & 3) * 16 + fr;
      *(bf16x8*)(&Ws[(size_t)((s * 4 + j) * 64 + l) * 8]) = bv;
    }
  }
  __syncthreads();  // the ONLY barrier

  float bj[4];
#pragma unroll
  for (int j = 0; j < 4; ++j) bj[j] = bias[bn + j * 16 + mrow];
  const __bf16* wsl = &Ws[lane * 8];

#pragma unroll
  for (int p = 0; p < 2; ++p) {
    const float* xp = xw + (size_t)p * 32 * K;
    f32x4 acc[2][4] = {};
#pragma unroll
    for (int s = 0; s < 16; ++s) {
      // prefetch next chunk (next strip's first chunk at s==15; self at end)
      const float* pn = (s < 15) ? (xp + (s + 1) * 32)
                                 : ((p == 0) ? (xp + 32 * K) : xp);
      f32x4 n0 = *(const f32x4*)(pn);
      f32x4 n1 = *(const f32x4*)(pn + 4);
      f32x4 n2 = *(const f32x4*)(pn + 16 * K);
      f32x4 n3 = *(const f32x4*)(pn + 16 * K + 4);
      __builtin_amdgcn_sched_barrier(0);  // pin: loads issue before compute

      bf16x8 a0, a1;
#pragma unroll
      for (int e = 0; e < 4; ++e) {
        a0[e]     = (__bf16)c0[e];
        a0[e + 4] = (__bf16)c1[e];
        a1[e]     = (__bf16)c2[e];
        a1[e + 4] = (__bf16)c3[e];
      }
      const __bf16* wp8 = wsl + s * 2048;          // (s*4)*64*8 elems
      bf16x8 b0 = *(const bf16x8*)(wp8);
      bf16x8 b1 = *(const bf16x8*)(wp8 + 512);     // j*64*8
      bf16x8 b2 = *(const bf16x8*)(wp8 + 1024);
      bf16x8 b3 = *(const bf16x8*)(wp8 + 1536);
      acc[0][0] = __builtin_amdgcn_mfma_f32_16x16x32_bf16(a0, b0, acc[0][0], 0, 0, 0);
      acc[0][1] = __builtin_amdgcn_mfma_f32_16x16x32_bf16(a0, b1, acc[0][1], 0, 0, 0);
      acc[0][2] = __builtin_amdgcn_mfma_f32_16x16x32_bf16(a0, b2, acc[0][2], 0, 0, 0);
      acc[0][3] = __builtin_amdgcn_mfma_f32_16x16x32_bf16(a0, b3, acc[0][3], 0, 0, 0);
      acc[1][0] = __builtin_amdgcn_mfma_f32_16x16x32_bf16(a1, b0, acc[1][0], 0, 0, 0);
      acc[1][1] = __builtin_amdgcn_mfma_f32_16x16x32_bf16(a1, b1, acc[1][1], 0, 0, 0);
      acc[1][2] = __builtin_amdgcn_mfma_f32_16x16x32_bf16(a1, b2, acc[1][2], 0, 0, 0);
      acc[1][3] = __builtin_amdgcn_mfma_f32_16x16x32_bf16(a1, b3, acc[1][3], 0, 0, 0);
      c0 = n0; c1 = n1; c2 = n2; c3 = n3;  // SSA-renamed, no real moves
    }
    // strip epilogue: C/D col = lane&15 (n), row = (lane>>4)*4 + rr (m)
    const size_t row0 = rowbase + (size_t)p * 32;
#pragma unroll
    for (int i2 = 0; i2 < 2; ++i2) {
#pragma unroll
      for (int rr = 0; rr < 4; ++rr) {
        const size_t gr = row0 + i2 * 16 + (lane >> 4) * 4 + rr;
        float* yp = Y + gr * N + bn + mrow;
#pragma unroll
        for (int j = 0; j < 4; ++j)
          __builtin_nontemporal_store(acc[i2][j][rr] + bj[j], yp + j * 16);
      }
    }
  }
}

extern "C" void kernel_launch(void* const* d_in, const int* in_sizes, int n_in,
                              void* d_out, int out_size, void* d_ws, size_t ws_size,
                              hipStream_t stream) {
  const float* X = (const float*)d_in[0];
  const float* W = (const float*)d_in[1];
  const float* b = (const float*)d_in[2];
  float* Y = (float*)d_out;
  linear_stream2<<<dim3(1024), 512, 0, stream>>>(X, W, b, Y);
}

// Round 5
// 260.113 us; speedup vs baseline: 1.8270x; 1.2690x over previous
//
#include <hip/hip_runtime.h>

// y = x @ W^T + bias. x:[65536,512] f32, W:[512,512] f32, bias:[512] f32.
// R7 (= R6 retried; previous bench died to container infra, kernel audited
//     clean for hangs/OOB/divergent barriers).
//   R5 post-mortem: BN=64 meant X re-read 8x = 1072 MB through L2/L3 at
//   ~7 TB/s = the whole 173 us. Fix the traffic, not the latency.
//   BM=256 x BN=256, BK=64, 512 blocks x 512 thr (8 waves, 2m x 4n,
//   128x64 per wave, acc[8][4] = 128 AGPR -> 1 block/CU, 2 waves/SIMD).
//   X re-read = 2x, and the n-pair of each m-tile runs concurrently on the
//   same XCD (id swizzle) -> second read L2-hit; W (1 MB) L2-hot everywhere.
//   HBM ~= 134 X + 134 Y = 43 us floor.
//   Single-buffer 64 KB LDS, 2 raw lgkm-only barriers per K-tile: vmcnt is
//   NEVER drained at a barrier -> tile t+1 global loads stay in flight
//   across the whole 64-MFMA phase.
//   LDS: linear 128 B rows + XOR swizzle (group ^= row&7, i.e. byte ^=
//   (row&7)<<4) -> frag ds_read_b128 is 2-way (free), no padding.

typedef __bf16 bf16x8 __attribute__((ext_vector_type(8)));
typedef float f32x4 __attribute__((ext_vector_type(4)));

// raw barrier: LDS ordering only, never waits vmcnt (rule #18: sched fence)
#define BAR() do { asm volatile("s_waitcnt lgkmcnt(0)" ::: "memory"); \
  __builtin_amdgcn_s_barrier(); __builtin_amdgcn_sched_barrier(0); } while (0)

__global__ __launch_bounds__(512, 2)
void linear_big(const float* __restrict__ X, const float* __restrict__ W,
                const float* __restrict__ bias, float* __restrict__ Y) {
  constexpr int K = 512, N = 512;

  // 256 rows x 64 k of bf16 = 128 B/row, 32 KB each. Logical 16B-group g of
  // row r lives at physical group g ^ (r & 7).
  __shared__ __bf16 As[256 * 64];
  __shared__ __bf16 Bs[256 * 64];

  const int tid  = threadIdx.x;
  const int lane = tid & 63;
  const int wave = tid >> 6;

  // 512 blocks = 256 m-tiles x 2 n-tiles. id = (mhi<<4)|(n<<3)|(m&7):
  // the two n-sharers of an m-tile differ by 8 -> same XCD (round-robin)
  // and adjacent in dispatch -> co-resident -> X second read is L2-hit.
  const int id = blockIdx.x;
  const int m  = ((id >> 4) << 3) | (id & 7);
  const int n  = (id >> 3) & 1;
  const int bm = m << 8;
  const int bn = n << 8;

  const int wm = (wave >> 2) << 7;  // 0 / 128
  const int wn = (wave & 3) << 6;   // 0..192

  // ---- staging map: thread t -> rows (t>>3)+64j, 16B-group g = t&7 ----
  const int srow  = tid >> 3;                 // 0..63
  const int g     = tid & 7;
  const int wbyte = srow * 128 + ((g ^ (srow & 7)) << 4);  // + j*8192
  const float* Xst = X + (size_t)(bm + srow) * K + g * 8;
  const float* Wst = W + (size_t)(bn + srow) * K + g * 8;

  // ---- frag-read bases: row = (wm|wn) + frag*16 + mrow, group (h*4+q)^m7 ----
  const int mrow = lane & 15;
  const int q    = lane >> 4;
  const int m7   = mrow & 7;
  const int ga0  = ((q ^ m7) << 4);         // ks half 0 (k 0..31)
  const int ga1  = (((q + 4) ^ m7) << 4);   // ks half 1 (k 32..63)
  const char* asb = (const char*)As + (wm + mrow) * 128;
  const char* bsb = (const char*)Bs + (wn + mrow) * 128;

  float bj[4];
#pragma unroll
  for (int j = 0; j < 4; ++j) bj[j] = bias[bn + wn + j * 16 + mrow];

  f32x4 xs[4][2], ws[4][2];

  auto load_tile = [&](int kt) {
#pragma unroll
    for (int j = 0; j < 4; ++j) {
      const float* xp = Xst + kt + (size_t)j * 64 * K;
      xs[j][0] = *(const f32x4*)xp;
      xs[j][1] = *(const f32x4*)(xp + 4);
      const float* wp = Wst + kt + (size_t)j * 64 * K;
      ws[j][0] = *(const f32x4*)wp;
      ws[j][1] = *(const f32x4*)(wp + 4);
    }
  };

  auto cvt_write = [&]() {
#pragma unroll
    for (int j = 0; j < 4; ++j) {
      bf16x8 av, bv;
#pragma unroll
      for (int e = 0; e < 4; ++e) {
        av[e]     = (__bf16)xs[j][0][e];
        av[e + 4] = (__bf16)xs[j][1][e];
        bv[e]     = (__bf16)ws[j][0][e];
        bv[e + 4] = (__bf16)ws[j][1][e];
      }
      *(bf16x8*)((char*)As + wbyte + j * 8192) = av;
      *(bf16x8*)((char*)Bs + wbyte + j * 8192) = bv;
    }
  };

  f32x4 acc[8][4] = {};

  // prologue
  load_tile(0);
  cvt_write();          // counted vmcnt waits on tile-0 loads
  BAR();
  load_tile(64);        // tile 1 in flight across the whole first MFMA phase
  __builtin_amdgcn_sched_barrier(0);

#pragma unroll 1
  for (int t = 0; t < 8; ++t) {
    // ---- MFMA phase: 24 ds_read_b128 + 64 MFMA per wave ----
#pragma unroll
    for (int h = 0; h < 2; ++h) {
      const int ga = h ? ga1 : ga0;
      bf16x8 bfr[4];
#pragma unroll
      for (int j = 0; j < 4; ++j)
        bfr[j] = *(const bf16x8*)(bsb + ga + j * 2048);
#pragma unroll
      for (int i2 = 0; i2 < 8; ++i2) {
        bf16x8 af = *(const bf16x8*)(asb + ga + i2 * 2048);
#pragma unroll
        for (int j = 0; j < 4; ++j)
          acc[i2][j] = __builtin_amdgcn_mfma_f32_16x16x32_bf16(af, bfr[j],
                                                               acc[i2][j], 0, 0, 0);
      }
    }
    if (t < 7) {
      BAR();                         // all frag reads done -> safe to overwrite
      cvt_write();                   // tile t+1 (counted vmcnt on its loads)
      if (t < 6) {
        load_tile((t + 2) * 64);     // stays in flight across next phase
        __builtin_amdgcn_sched_barrier(0);
      }
      BAR();                         // writes visible; vmcnt NOT drained
    }
  }

  // ---- epilogue: C/D col = lane&15 (n), row = (lane>>4)*4 + r (m) ----
#pragma unroll
  for (int i2 = 0; i2 < 8; ++i2) {
#pragma unroll
    for (int r = 0; r < 4; ++r) {
      const size_t gr = (size_t)(bm + wm + i2 * 16 + q * 4 + r);
      float* yp = Y + gr * N + bn + wn + mrow;
#pragma unroll
      for (int j = 0; j < 4; ++j)
        __builtin_nontemporal_store(acc[i2][j][r] + bj[j], yp + j * 16);
    }
  }
}

extern "C" void kernel_launch(void* const* d_in, const int* in_sizes, int n_in,
                              void* d_out, int out_size, void* d_ws, size_t ws_size,
                              hipStream_t stream) {
  const float* X = (const float*)d_in[0];
  const float* W = (const float*)d_in[1];
  const float* b = (const float*)d_in[2];
  float* Y = (float*)d_out;
  linear_big<<<dim3(512), 512, 0, stream>>>(X, W, b, Y);
}